// Round 6
// baseline (160.404 us; speedup 1.0000x reference)
//
#include <hip/hip_runtime.h>

typedef __attribute__((ext_vector_type(4))) float f32x4;
typedef __attribute__((ext_vector_type(8))) short bf16x8;

#define D_MODEL 1024
#define NQK     2048
#define LSEQ    2048
#define NB      4
#define NX4     2097152   // 8192*1024/4
#define NW4     524288    // 2048*1024/4

__device__ inline unsigned short f2bf(float f) {
  unsigned u = __float_as_uint(f);
  unsigned r = (u + 0x7FFFu + ((u >> 16) & 1u)) >> 16;
  return (unsigned short)r;
}

__device__ inline void gl_lds16(const void* g, void* l) {
  __builtin_amdgcn_global_load_lds((const __attribute__((address_space(1))) void*)g,
                                   (__attribute__((address_space(3))) void*)l, 16, 0, 0);
}

// ---------------- fp32 -> bf16 convert (X then W) + colsum zeroing ----------------
__global__ __launch_bounds__(256) void cvt_zero_kernel(
    const float4* __restrict__ X, const float4* __restrict__ W,
    ushort4* __restrict__ dst, float* __restrict__ colsum) {
  int i = blockIdx.x * 256 + threadIdx.x;
  if (blockIdx.x < 32) colsum[i] = 0.f;          // zero colsum[8192]
  float4 v = (i < NX4) ? X[i] : W[i - NX4];
  ushort4 o;
  o.x = f2bf(v.x); o.y = f2bf(v.y); o.z = f2bf(v.z); o.w = f2bf(v.w);
  dst[i] = o;
}

// ---------------- GEMM: Q,K = X W^T + bias, stored as fp8 e4m3 (unscaled) ----------------
__global__ __launch_bounds__(256) void gemm_qk(
    const unsigned short* __restrict__ Xb,   // [8192][1024] bf16
    const unsigned short* __restrict__ Wb,   // [2048][1024] bf16
    const float* __restrict__ bias,          // [3072]
    unsigned char* __restrict__ C)           // [8192][2048] fp8 e4m3
{
  __shared__ unsigned short As[128 * 32];  // 8KB
  __shared__ unsigned short Bs[128 * 32];  // 8KB
  int t = threadIdx.x;
  int w = t >> 6, lane = t & 63;
  int l15 = lane & 15, lg = lane >> 4;
  int bid = blockIdx.x;
  int k2 = bid >> 3, xcd = bid & 7;
  int m0 = (xcd * 8 + (k2 >> 4)) * 128;
  int n0 = (k2 & 15) * 128;
  int wm = (w >> 1) * 64, wn = (w & 1) * 64;
  f32x4 acc[4][4] = {};

  for (int kt = 0; kt < D_MODEL / 32; ++kt) {
#pragma unroll
    for (int i = 0; i < 2; ++i) {
      int ob = w * 1024 + i * 4096;
      int o = ob + lane * 16;
      int row = o >> 6;
      int kb = (o & 63) ^ (((row >> 1) & 3) << 4);
      gl_lds16(Xb + (m0 + row) * D_MODEL + kt * 32 + (kb >> 1), (char*)As + ob);
      gl_lds16(Wb + (n0 + row) * D_MODEL + kt * 32 + (kb >> 1), (char*)Bs + ob);
    }
    __syncthreads();
    bf16x8 a[4], b[4];
#pragma unroll
    for (int mi = 0; mi < 4; mi++) {
      int row = wm + mi * 16 + l15;
      int kb = (lg * 16) ^ (((row >> 1) & 3) << 4);
      a[mi] = *(const bf16x8*)((const char*)As + row * 64 + kb);
    }
#pragma unroll
    for (int ni = 0; ni < 4; ni++) {
      int row = wn + ni * 16 + l15;
      int kb = (lg * 16) ^ (((row >> 1) & 3) << 4);
      b[ni] = *(const bf16x8*)((const char*)Bs + row * 64 + kb);
    }
#pragma unroll
    for (int mi = 0; mi < 4; mi++)
#pragma unroll
      for (int ni = 0; ni < 4; ni++)
        acc[mi][ni] = __builtin_amdgcn_mfma_f32_16x16x32_bf16(a[mi], b[ni], acc[mi][ni], 0, 0, 0);
    __syncthreads();
  }

#pragma unroll
  for (int ni = 0; ni < 4; ni++) {
    int n = n0 + wn + ni * 16 + l15;
    float bv = bias[n];
#pragma unroll
    for (int mi = 0; mi < 4; mi++) {
      int mbase = m0 + wm + mi * 16 + lg * 4;
#pragma unroll
      for (int r = 0; r < 4; r++) {
        float v = acc[mi][ni][r] + bv;
        unsigned u = __builtin_amdgcn_cvt_pk_fp8_f32(v, v, 0, false);
        C[(size_t)(mbase + r) * NQK + n] = (unsigned char)u;
      }
    }
  }
}

// ---------------- fused attention column sums (fp8, 16 waves, shared K strips) ----------------
// wg = 1024 threads (16 waves = 2m x 8n). wg covers 64 q-rows x all 2048 keys of one (b,h).
// Strip wn (256 keys) is staged 16-keys-at-a-time into a shared double-buffered 2x4KB LDS
// slice by its two m-partner waves. Raw barriers + counted vmcnt(2) keep loads in flight.
__global__ __launch_bounds__(1024, 4) void attn_fused(
    const unsigned char* __restrict__ C,   // [8192][2048] fp8
    float* __restrict__ colsum)            // [4][2048]
{
  __shared__ unsigned char Ks[65536];      // 8 strips x 2 bufs x 4KB
  int t = threadIdx.x;
  int w = t >> 6, lane = t & 63;
  int wm = w >> 3, wn = w & 7;
  int l15 = lane & 15, lg = lane >> 4;

  // XCD swizzle: 64 consecutive nids (2 bh) per XCD -> K slice (1MB fp8) L2-resident
  int nid = (blockIdx.x & 7) * 64 + (blockIdx.x >> 3);
  int bh = nid >> 5, qblk = nid & 31;
  int b = bh >> 2, h = bh & 3;

  const unsigned char* Qbase = C + (size_t)(b * LSEQ + qblk * 64 + wm * 32) * NQK + h * 256;
  const unsigned char* Kbase = C + (size_t)(b * LSEQ) * NQK + 1024 + h * 256;
  unsigned char* strip = Ks + wn * 8192;

  // Q fragments: 32 rows x 256 hd fp8 (A-operand layout), 32 VGPRs
  long qf[2][8];
#pragma unroll
  for (int mi = 0; mi < 2; mi++)
#pragma unroll
    for (int kk = 0; kk < 8; kk++)
      qf[mi][kk] = *(const long*)(Qbase + (size_t)(mi * 16 + l15) * NQK + kk * 32 + lg * 8);
  asm volatile("s_waitcnt vmcnt(0)" ::: "memory");   // drain Q so vmcnt counts are exact
  __builtin_amdgcn_sched_barrier(0);

  float zacc[2][4] = {};
  unsigned E[16][2];                       // exp(S) packed 4x e4m3 per u32
  int swz = (l15 & 7) << 4;

  // wave stages its half (8 keys) of strip wn's 16-key tile: 2 x gl_lds16
#define STAGE(nn, bi)                                                          \
  {                                                                            \
    _Pragma("unroll")                                                          \
    for (int j = 0; j < 2; j++) {                                              \
      int i = wm * 2 + j;                                                      \
      int o = i * 1024 + lane * 16;                                            \
      int s = o >> 8;                                                          \
      int db = (o & 255) ^ ((s & 7) << 4);                                     \
      gl_lds16(Kbase + (size_t)(wn * 256 + (nn) * 16 + s) * NQK + db,          \
               strip + (bi) * 4096 + o);                                       \
    }                                                                          \
  }

  STAGE(0, 0);

#pragma unroll
  for (int n = 0; n < 16; n++) {
    int bi = n & 1;
    __builtin_amdgcn_sched_barrier(0);
    __builtin_amdgcn_s_barrier();                    // B1: all done computing tile n-1
    if (n < 15) {
      STAGE(n + 1, bi ^ 1);
      asm volatile("s_waitcnt vmcnt(2)" ::: "memory"); // my tile-n loads landed, n+1 in flight
    } else {
      asm volatile("s_waitcnt vmcnt(0)" ::: "memory");
    }
    __builtin_amdgcn_sched_barrier(0);
    __builtin_amdgcn_s_barrier();                    // B2: tile n fully in LDS
    __builtin_amdgcn_sched_barrier(0);

    const unsigned char* bufp = strip + bi * 4096;
    f32x4 acc0 = {}, acc1 = {};
#pragma unroll
    for (int kk = 0; kk < 8; kk++) {
      long kf = *(const long*)(bufp + l15 * 256 + ((kk * 32 + lg * 8) ^ swz));
      acc0 = __builtin_amdgcn_mfma_f32_16x16x32_fp8_fp8(qf[0][kk], kf, acc0, 0, 0, 0);
      acc1 = __builtin_amdgcn_mfma_f32_16x16x32_fp8_fp8(qf[1][kk], kf, acc1, 0, 0, 0);
    }
    {
      float e0 = __expf(acc0[0] * 0.0625f), e1 = __expf(acc0[1] * 0.0625f);
      float e2 = __expf(acc0[2] * 0.0625f), e3 = __expf(acc0[3] * 0.0625f);
      zacc[0][0] += e0; zacc[0][1] += e1; zacc[0][2] += e2; zacc[0][3] += e3;
      unsigned u = __builtin_amdgcn_cvt_pk_fp8_f32(e0, e1, 0, false);
      E[n][0] = __builtin_amdgcn_cvt_pk_fp8_f32(e2, e3, (int)u, true);
    }
    {
      float e0 = __expf(acc1[0] * 0.0625f), e1 = __expf(acc1[1] * 0.0625f);
      float e2 = __expf(acc1[2] * 0.0625f), e3 = __expf(acc1[3] * 0.0625f);
      zacc[1][0] += e0; zacc[1][1] += e1; zacc[1][2] += e2; zacc[1][3] += e3;
      unsigned u = __builtin_amdgcn_cvt_pk_fp8_f32(e0, e1, 0, false);
      E[n][1] = __builtin_amdgcn_cvt_pk_fp8_f32(e2, e3, (int)u, true);
    }
  }
#undef STAGE

  // ---- Z combine across the 8 key-strip waves of each m-half ----
  __syncthreads();
  float* Zpf = (float*)Ks;                 // [16][32]
#pragma unroll
  for (int mi = 0; mi < 2; mi++)
#pragma unroll
    for (int r = 0; r < 4; r++) {
      float z = zacc[mi][r];
      z += __shfl_xor(z, 1, 64);
      z += __shfl_xor(z, 2, 64);
      z += __shfl_xor(z, 4, 64);
      z += __shfl_xor(z, 8, 64);
      if (l15 == 0) Zpf[w * 32 + mi * 16 + lg * 4 + r] = z;
    }
  __syncthreads();

  float invz[2][4];
#pragma unroll
  for (int mi = 0; mi < 2; mi++) {
    f32x4 s = {};
#pragma unroll
    for (int j = 0; j < 8; j++) {
      f32x4 p = *(const f32x4*)(Zpf + (wm * 8 + j) * 32 + mi * 16 + lg * 4);
      s += p;
    }
    invz[mi][0] = 1.0f / s[0]; invz[mi][1] = 1.0f / s[1];
    invz[mi][2] = 1.0f / s[2]; invz[mi][3] = 1.0f / s[3];
  }

  // ---- column sums straight from register-resident fp8 E ----
#pragma unroll
  for (int n = 0; n < 16; n++) {
    float c = 0.f;
#pragma unroll
    for (int mi = 0; mi < 2; mi++) {
      c += __builtin_amdgcn_cvt_f32_fp8(E[n][mi], 0) * invz[mi][0];
      c += __builtin_amdgcn_cvt_f32_fp8(E[n][mi], 1) * invz[mi][1];
      c += __builtin_amdgcn_cvt_f32_fp8(E[n][mi], 2) * invz[mi][2];
      c += __builtin_amdgcn_cvt_f32_fp8(E[n][mi], 3) * invz[mi][3];
    }
    c += __shfl_xor(c, 16, 64);
    c += __shfl_xor(c, 32, 64);
    if (lane < 16)
      atomicAdd(&colsum[b * LSEQ + wn * 256 + n * 16 + l15], c);
  }
}

// ---------------- finalize ----------------
__global__ __launch_bounds__(256) void finalize_kernel(
    const float* __restrict__ colsum, float* __restrict__ out) {
  __shared__ float red[256];
  int t = threadIdx.x;
  float acc = 0.f;
  for (int i = t; i < NB * LSEQ; i += 256) {
    float aw = colsum[i] * (1.0f / 8192.0f) + 1e-8f;
    acc += -aw * __logf(aw);
  }
  red[t] = acc;
  __syncthreads();
  for (int s = 128; s > 0; s >>= 1) {
    if (t < s) red[t] += red[t + s];
    __syncthreads();
  }
  if (t == 0) {
    float me = red[0] * 0.25f;
    out[0] = 1.0f / (1.0f + __expf(-me));
  }
}

extern "C" void kernel_launch(void* const* d_in, const int* in_sizes, int n_in,
                              void* d_out, int out_size, void* d_ws, size_t ws_size,
                              hipStream_t stream) {
  const float* hs   = (const float*)d_in[0];   // [4,2048,1024]
  const float* wgt  = (const float*)d_in[1];   // [3072,1024]
  const float* bias = (const float*)d_in[2];   // [3072]
  float* out = (float*)d_out;
  char* ws = (char*)d_ws;

  unsigned short* Xb = (unsigned short*)(ws);                   // 16 MB
  unsigned short* Wb = (unsigned short*)(ws + (16u << 20));     // 4 MB
  unsigned char*  C8 = (unsigned char*)(ws + (20u << 20));      // 16 MB fp8
  float* colsum = (float*)(ws + (36u << 20));                   // 32 KB

  cvt_zero_kernel<<<(NX4 + NW4) / 256, 256, 0, stream>>>(
      (const float4*)hs, (const float4*)wgt, (ushort4*)Xb, colsum);

  gemm_qk<<<1024, 256, 0, stream>>>(Xb, Wb, bias, C8);

  attn_fused<<<512, 1024, 0, stream>>>(C8, colsum);
  finalize_kernel<<<1, 256, 0, stream>>>(colsum, out);
}